// Round 12
// baseline (236.603 us; speedup 1.0000x reference)
//
#include <hip/hip_runtime.h>

// Problem shape (fixed by setup_inputs): B=4, N=16384, M=4096, C=64, K=32
static constexpr int Bn = 4;
static constexpr int Nn = 16384;
static constexpr int Mn = 4096;
static constexpr int Cn = 64;
static constexpr int Kn = 32;

static constexpr int WPB     = 8;            // waves per block, 1 query/wave
static constexpr int THREADS = WPB * 64;     // 512
static constexpr int LSLOTS  = 40;           // surrogate top-LSLOTS kept
static constexpr int G       = 16;           // grid cells per axis
static constexpr int DMAX    = 6;            // shell table depth
static constexpr int NTAB    = 2197;         // 13^3 offsets
static constexpr int BUF     = 1024;         // per-wave candidate buffer
static constexpr float EPS   = 4e-3f;        // surrogate-vs-exact margin

typedef unsigned long long ull;
typedef unsigned int u32;

#define NEG_INF (-__builtin_inff())

// ---------------- wave primitives (VALU/DPP, no DS where possible) --------
__device__ __forceinline__ u32 dpp_shr1(u32 v) {
  return (u32)__builtin_amdgcn_update_dpp((int)v, (int)v, 0x138, 0xf, 0xf, false);
}
__device__ __forceinline__ u32 rdlane(u32 v, int l) {
  return (u32)__builtin_amdgcn_readlane((int)v, l);
}
__device__ __forceinline__ float rdlane_f(float v, int l) {
  return __uint_as_float(rdlane(__float_as_uint(v), l));
}

// monotone float<->uint order-preserving encoding
__device__ __forceinline__ u32 fenc(float f) {
  u32 u = __float_as_uint(f);
  return (u >> 31) ? ~u : (u | 0x80000000u);
}
__device__ __forceinline__ float fdec(u32 u) {
  return __uint_as_float((u >> 31) ? (u ^ 0x80000000u) : ~u);
}

// full-wave bitonic sort, ascending across 64 lanes (64-bit keys)
__device__ __forceinline__ ull sort64_asc(ull key, int lane) {
#pragma unroll
  for (int k = 2; k <= 64; k <<= 1) {
#pragma unroll
    for (int j = k >> 1; j > 0; j >>= 1) {
      const ull other = __shfl_xor(key, j);
      const bool keep_min = ((lane & j) == 0) == ((lane & k) == 0);
      const bool take = keep_min ? (other < key) : (other > key);
      key = take ? other : key;
    }
  }
  return key;
}

// total order (s desc, idx asc): is (s,i) strictly better than (ts,ti)?
__device__ __forceinline__ bool better(float s, u32 i, float ts, u32 ti) {
  return (s > ts) || (s == ts && i < ti);
}

// Insert into DESCENDING (s, idx-asc-on-tie) top-40 list; lanes>=40 = -inf.
// Set-deterministic: final list == top-40 of candidate SET by total order.
__device__ __forceinline__ void ins40(float kj, u32 ki,
                                      float& lst_s, u32& lst_i,
                                      float& tau_s, u32& tau_i, int lane) {
  const bool above = (lst_s > kj) || (lst_s == kj && lst_i < ki);
  const int pos = (int)__popcll(__ballot(above));
  const float shd = __uint_as_float(dpp_shr1(__float_as_uint(lst_s)));
  const u32  shi = dpp_shr1(lst_i);
  float nd = (lane == pos) ? kj : shd;
  u32   ni = (lane == pos) ? ki : shi;
  nd = (lane < pos) ? lst_s : nd;
  ni = (lane < pos) ? lst_i : ni;
  if (lane < LSLOTS) { lst_s = nd; lst_i = ni; }
  tau_s = rdlane_f(lst_s, LSLOTS - 1);
  tau_i = rdlane(lst_i, LSLOTS - 1);
}

// ---------------- constexpr Chebyshev-shell offset table ----------------
struct ShellTab {
  int start[DMAX + 2];
  u32 off[NTAB];   // (dx+8) | (dy+8)<<8 | (dz+8)<<16, shell-major
};
constexpr ShellTab mk_tab() {
  ShellTab t{};
  int p = 0;
  for (int d = 0; d <= DMAX; ++d) {
    t.start[d] = p;
    for (int dz = -d; dz <= d; ++dz)
      for (int dy = -d; dy <= d; ++dy)
        for (int dx = -d; dx <= d; ++dx) {
          int ax = dx < 0 ? -dx : dx;
          int ay = dy < 0 ? -dy : dy;
          int az = dz < 0 ? -dz : dz;
          int ch = ax > ay ? ax : ay; ch = ch > az ? ch : az;
          if (ch == d)
            t.off[p++] = (u32)((dx + 8) | ((dy + 8) << 8) | ((dz + 8) << 16));
        }
  }
  t.start[DMAX + 1] = p;
  return t;
}
__constant__ ShellTab g_tab = mk_tab();

// cell coordinate (clamped; identical expression everywhere => deterministic)
__device__ __forceinline__ int cellc(float v, float lo, float iv) {
  int c = (int)((v - lo) * iv);
  return c < 0 ? 0 : (c > G - 1 ? G - 1 : c);
}

// ---------------- kernel 0: F [B,C,N] -> FT [B,N,C] ----------------
__global__ __launch_bounds__(256) void transpose_f(
    const float* __restrict__ F, float* __restrict__ FT) {
  __shared__ float t[64][65];
  const int tid = threadIdx.x;
  const int bid = blockIdx.x;                 // 256 blocks
  const int xcd = bid & 7;
  const int b   = xcd >> 1;
  const int nt  = (bid >> 3) * 2 + (xcd & 1);
  const float* Fb = F + (size_t)b * Cn * Nn;
  float* FTb = FT + (size_t)b * Nn * Cn;
  for (int sub = 0; sub < 4; ++sub) {
    const int nbase = nt * 256 + sub * 64;
#pragma unroll
    for (int i = 0; i < 16; ++i) {
      const int c = (tid >> 6) + 4 * i;
      t[c][tid & 63] = Fb[(size_t)c * Nn + nbase + (tid & 63)];
    }
    __syncthreads();
#pragma unroll
    for (int i = 0; i < 16; ++i) {
      const int nn = (tid >> 6) + 4 * i;
      FTb[(size_t)(nbase + nn) * Cn + (tid & 63)] = t[tid & 63][nn];
    }
    __syncthreads();
  }
}

// ---------------- binning prep kernels ----------------
__global__ __launch_bounds__(1024) void k_init(u32* cursor, u32* bbox) {
  const int tid = threadIdx.x;
  for (int i = tid; i < Bn * 4097; i += 1024) cursor[i] = 0u;
  if (tid < Bn * 8) bbox[tid] = ((tid & 7) < 3) ? 0xFFFFFFFFu : 0u;
}

__global__ __launch_bounds__(256) void k_bbox(const float* __restrict__ P,
                                              u32* bbox) {
  const int gid = blockIdx.x * 256 + threadIdx.x;
  const int b = gid >> 14, i = gid & 16383;
  const float* Pb = P + (size_t)b * 3 * Nn;
  u32 ex = fenc(Pb[i]), ey = fenc(Pb[Nn + i]), ez = fenc(Pb[2 * Nn + i]);
  u32 mnx = ex, mny = ey, mnz = ez, mxx = ex, mxy = ey, mxz = ez;
#pragma unroll
  for (int j = 1; j < 64; j <<= 1) {
    u32 t;
    t = (u32)__shfl_xor((int)mnx, j); mnx = mnx < t ? mnx : t;
    t = (u32)__shfl_xor((int)mny, j); mny = mny < t ? mny : t;
    t = (u32)__shfl_xor((int)mnz, j); mnz = mnz < t ? mnz : t;
    t = (u32)__shfl_xor((int)mxx, j); mxx = mxx > t ? mxx : t;
    t = (u32)__shfl_xor((int)mxy, j); mxy = mxy > t ? mxy : t;
    t = (u32)__shfl_xor((int)mxz, j); mxz = mxz > t ? mxz : t;
  }
  if ((threadIdx.x & 63) == 0) {
    atomicMin(&bbox[b * 8 + 0], mnx);
    atomicMin(&bbox[b * 8 + 1], mny);
    atomicMin(&bbox[b * 8 + 2], mnz);
    atomicMax(&bbox[b * 8 + 3], mxx);
    atomicMax(&bbox[b * 8 + 4], mxy);
    atomicMax(&bbox[b * 8 + 5], mxz);
  }
}

__device__ __forceinline__ int binof(float x, float y, float z,
                                     const u32* bb) {
  const float b0x = fdec(bb[0]), b0y = fdec(bb[1]), b0z = fdec(bb[2]);
  const float b1x = fdec(bb[3]), b1y = fdec(bb[4]), b1z = fdec(bb[5]);
  const float ivx = (float)G / (b1x - b0x);
  const float ivy = (float)G / (b1y - b0y);
  const float ivz = (float)G / (b1z - b0z);
  const int cx = cellc(x, b0x, ivx);
  const int cy = cellc(y, b0y, ivy);
  const int cz = cellc(z, b0z, ivz);
  return (cz * G + cy) * G + cx;
}

__global__ __launch_bounds__(256) void k_hist(const float* __restrict__ P,
                                              const u32* __restrict__ bbox,
                                              u32* cursor) {
  const int gid = blockIdx.x * 256 + threadIdx.x;
  const int b = gid >> 14, i = gid & 16383;
  const float* Pb = P + (size_t)b * 3 * Nn;
  const int bin = binof(Pb[i], Pb[Nn + i], Pb[2 * Nn + i], bbox + b * 8);
  atomicAdd(&cursor[b * 4097 + bin], 1u);
}

__global__ __launch_bounds__(1024) void k_scan(u32* cursor, u32* binStart) {
  __shared__ u32 sm[1024];
  const int b = blockIdx.x, tid = threadIdx.x;
  u32* cur = cursor + b * 4097;
  u32* bs  = binStart + b * 4097;
  u32 v[4], loc = 0;
#pragma unroll
  for (int j = 0; j < 4; ++j) { v[j] = cur[tid * 4 + j]; loc += v[j]; }
  sm[tid] = loc;
  __syncthreads();
  for (int off = 1; off < 1024; off <<= 1) {
    const u32 t = (tid >= off) ? sm[tid - off] : 0u;
    __syncthreads();
    sm[tid] += t;
    __syncthreads();
  }
  u32 s = sm[tid] - loc;   // exclusive
#pragma unroll
  for (int j = 0; j < 4; ++j) {
    bs[tid * 4 + j] = s;
    cur[tid * 4 + j] = s;
    s += v[j];
  }
  if (tid == 1023) bs[4096] = s;   // == Nn
}

__global__ __launch_bounds__(256) void k_scatter(const float* __restrict__ P,
                                                 const u32* __restrict__ bbox,
                                                 u32* cursor,
                                                 float4* __restrict__ pts4,
                                                 u32* __restrict__ pidx) {
#pragma clang fp contract(off)
  const int gid = blockIdx.x * 256 + threadIdx.x;
  const int b = gid >> 14, i = gid & 16383;
  const float* Pb = P + (size_t)b * 3 * Nn;
  const float x = Pb[i], y = Pb[Nn + i], z = Pb[2 * Nn + i];
  const int bin = binof(x, y, z, bbox + b * 8);
  const u32 pos = atomicAdd(&cursor[b * 4097 + bin], 1u);
  const float h = -0.5f * ((x * x + y * y) + z * z);   // reference xx order
  pts4[((size_t)b << 14) + pos] = make_float4(x, y, z, h);
  pidx[((size_t)b << 14) + pos] = (u32)i;
}

// ---------------- kernel B: binned kNN + grouped gather ----------------
// Numerics contract (bit-matches jax-GPU expected AND np reference) applies
// to the FINAL exact phase only:
//   xx  = (x*x + y*y) + z*z ; dot = fma(z,qz, fma(y,qy, x*qx))
//   dist= max((xx + yy) - 2*dot, 0)
// Scan keeps top-40 by surrogate s = dot - xx/2 under total order
// (s desc, idx asc) — set-deterministic regardless of scatter order.
// Shell stop bound: points beyond shell d have dist^2 >= ((d-1)*hmin)^2;
// stop when that > yy - 2*s32 + EPS (s32 = 32nd surrogate).
__global__ __launch_bounds__(THREADS, 4) void knn_bin(
    const float* __restrict__ P, const float* __restrict__ Q,
    const float* __restrict__ FT, const float4* __restrict__ pts4,
    const u32* __restrict__ pidx, const u32* __restrict__ binStart,
    const u32* __restrict__ bbox, float* __restrict__ out) {
#pragma clang fp contract(off)
  __shared__ u32 sbuf[WPB][BUF];   // 32 KiB

  const int tid  = threadIdx.x;
  const int lane = tid & 63;
  const int wid  = tid >> 6;
  const int bid  = blockIdx.x;          // 2048
  const int xcd  = bid & 7;
  const int b    = xcd >> 1;
  const int tile = (bid >> 3) * 2 + (xcd & 1);
  const int m    = tile * WPB + wid;

  const float* Pb = P + (size_t)b * 3 * Nn;
  const float* Qb = Q + (size_t)b * 3 * Mn;

  const float qx = Qb[m];
  const float qy = Qb[Mn + m];
  const float qz = Qb[2 * Mn + m];
  const float yyq = (qx * qx + qy * qy) + qz * qz;

  const u32* bb = bbox + b * 8;
  const float b0x = fdec(bb[0]), b0y = fdec(bb[1]), b0z = fdec(bb[2]);
  const float b1x = fdec(bb[3]), b1y = fdec(bb[4]), b1z = fdec(bb[5]);
  const float ivx = (float)G / (b1x - b0x);
  const float ivy = (float)G / (b1y - b0y);
  const float ivz = (float)G / (b1z - b0z);
  const float hmin = fminf((b1x - b0x), fminf((b1y - b0y), (b1z - b0z))) *
                     (1.0f / G);
  const int cix = cellc(qx, b0x, ivx);
  const int ciy = cellc(qy, b0y, ivy);
  const int ciz = cellc(qz, b0z, ivz);

  const u32* bs = binStart + b * 4097;
  const float4* pp4 = pts4 + ((size_t)b << 14);
  const u32* pid4 = pidx + ((size_t)b << 14);
  u32* wbuf = sbuf[wid];

  float lst_s = NEG_INF; u32 lst_i = 0u;
  float tau_s = NEG_INF; u32 tau_i = 0xFFFFFFFFu;
  bool first = true, done = false;

  for (int d = 0; d <= DMAX + 1; ++d) {
    if (d >= 2) {
      const float s32 = rdlane_f(lst_s, 31);
      if (s32 > NEG_INF) {
        const float gd = (float)(d - 1) * hmin;
        if (gd * gd > yyq - 2.0f * s32 + EPS) { done = true; break; }
      }
    }
    if (d > DMAX) break;
    const int cs = g_tab.start[d], ce = g_tab.start[d + 1];
    for (int cb = cs; cb < ce; cb += 64) {
      const int cn = ce - cb;
      u32 st = 0, cnt = 0;
      if (lane < cn) {
        const u32 e = g_tab.off[cb + lane];
        const int cx = cix + (int)(e & 0xFFu) - 8;
        const int cy = ciy + (int)((e >> 8) & 0xFFu) - 8;
        const int cz = ciz + (int)((e >> 16) & 0xFFu) - 8;
        if ((u32)cx < (u32)G && (u32)cy < (u32)G && (u32)cz < (u32)G) {
          const int bin = (cz * G + cy) * G + cx;
          st = bs[bin];
          cnt = bs[bin + 1] - st;
        }
      }
      u32 incl = cnt;
#pragma unroll
      for (int j = 1; j < 64; j <<= 1) {
        const u32 t = (u32)__shfl_up((int)incl, j);
        if (lane >= j) incl += t;
      }
      const u32 total = rdlane(incl, 63);
      const u32 excl = incl - cnt;
      for (u32 slice = 0; slice < total; slice += BUF) {
        const u32 se = total < slice + BUF ? total : slice + BUF;
        const u32 wlo = excl > slice ? excl : slice;
        const u32 whi = (excl + cnt) < se ? (excl + cnt) : se;
        for (u32 t = wlo; t < whi; ++t) wbuf[t - slice] = st + (t - excl);
        asm volatile("s_waitcnt lgkmcnt(0)" ::: "memory");
        const u32 ns = se - slice;
        for (u32 t0 = 0; t0 < ns; t0 += 64) {
          const bool act = (t0 + (u32)lane) < ns;
          u32 rdix = t0 + (u32)lane;
          if (!act) rdix = 0;
          const u32 ppos = wbuf[rdix];
          const float4 pv = pp4[ppos];
          const u32 pid = pid4[ppos];
          float s = fmaf(pv.z, qz, fmaf(pv.y, qy, fmaf(pv.x, qx, pv.w)));
          if (first) {
            first = false;   // warm start: sort the first batch, take top-40
            const float ss = act ? s : NEG_INF;
            const u32 os = fenc(ss);
            ull key = (((ull)(~os)) << 32) | (ull)pid;  // asc => s desc, idx asc
            key = sort64_asc(key, lane);
            const u32 osr = ~((u32)(key >> 32));
            const float sr = fdec(osr);
            if (lane < LSLOTS) { lst_s = sr; lst_i = (u32)(key & 0xFFFFFFFFull); }
            tau_s = rdlane_f(lst_s, LSLOTS - 1);
            tau_i = rdlane(lst_i, LSLOTS - 1);
          } else {
            if (!act) s = __builtin_nanf("");   // NaN: all compares false
            ull mm = __ballot(better(s, pid, tau_s, tau_i));
            while (mm) {
              const int src = (int)__builtin_ctzll(mm);
              mm &= mm - 1;
              const float kj = rdlane_f(s, src);
              const u32 ki = rdlane(pid, src);
              if (better(kj, ki, tau_s, tau_i))
                ins40(kj, ki, lst_s, lst_i, tau_s, tau_i, lane);
              mm &= __ballot(better(s, pid, tau_s, tau_i));
            }
          }
        }
      }
    }
  }

  if (!done) {
    // rare fallback (far outlier / bound never closed): exact by brute force
    lst_s = NEG_INF; lst_i = 0u; tau_s = NEG_INF; tau_i = 0xFFFFFFFFu;
    for (u32 t0 = 0; t0 < (u32)Nn; t0 += 64) {
      const u32 ppos = t0 + (u32)lane;
      const float4 pv = pp4[ppos];
      const u32 pid = pid4[ppos];
      const float s = fmaf(pv.z, qz, fmaf(pv.y, qy, fmaf(pv.x, qx, pv.w)));
      ull mm = __ballot(better(s, pid, tau_s, tau_i));
      while (mm) {
        const int src = (int)__builtin_ctzll(mm);
        mm &= mm - 1;
        const float kj = rdlane_f(s, src);
        const u32 ki = rdlane(pid, src);
        if (better(kj, ki, tau_s, tau_i))
          ins40(kj, ki, lst_s, lst_i, tau_s, tau_i, lane);
        mm &= __ballot(better(s, pid, tau_s, tau_i));
      }
    }
  }

  // ---- final: exact reference distance for survivors, sort, take 32 ----
  ull key;
  {
    const int idx = (int)lst_i;
    const float x = Pb[idx];
    const float y = Pb[Nn + idx];
    const float z = Pb[2 * Nn + idx];
    const float xx = (x * x + y * y) + z * z;
    const float dot = fmaf(z, qz, fmaf(y, qy, x * qx));
    const float dd = fmaxf((xx + yyq) - 2.0f * dot, 0.0f);
    key = (lane < LSLOTS && lst_s > NEG_INF)
            ? ((((ull)__float_as_uint(dd)) << 32) | (u32)idx)
            : ~0ull;
    key = sort64_asc(key, lane);   // (d asc, idx asc); top-32 in lanes 0..31
  }

  // ---- output: [B, 3+C, M, K] ----
  const size_t MK = (size_t)Mn * Kn;
  float* outb = out + (size_t)b * (3 + Cn) * MK;

  if (lane < 32) {
    const int idx = (int)(key & 0xFFFFFFFFull);
    const float px = Pb[idx];
    const float py = Pb[Nn + idx];
    const float pz = Pb[2 * Nn + idx];
    outb[0 * MK + (size_t)m * Kn + lane] = px - qx;
    outb[1 * MK + (size_t)m * Kn + lane] = py - qy;
    outb[2 * MK + (size_t)m * Kn + lane] = pz - qz;
  }

  const float* FTb = FT + (size_t)b * Nn * Cn;
  const int r  = lane & 15;
  const int qh = lane >> 4;
#pragma unroll
  for (int p2 = 0; p2 < 2; ++p2) {
    const int k = p2 * 16 + r;
    const int idxk = (int)(__shfl(key, k) & 0xFFFFFFFFull);
    const float* row = FTb + (size_t)idxk * Cn;
    float4 v[4];
#pragma unroll
    for (int i = 0; i < 4; ++i)
      v[i] = *(const float4*)(row + (qh + 4 * i) * 4);
#pragma unroll
    for (int i = 0; i < 4; ++i) {
      const int c = (qh + 4 * i) * 4;
      float* o = outb + (size_t)(3 + c) * MK + (size_t)m * Kn + k;
      o[0 * MK] = v[i].x;
      o[1 * MK] = v[i].y;
      o[2 * MK] = v[i].z;
      o[3 * MK] = v[i].w;
    }
  }
}

// ---------------- fallback full-scan kernel (R11, proven 188 µs) ----------
static constexpr int CHUNK  = 2048;
static constexpr int NCHUNK = Nn / CHUNK;
static constexpr int NGROUP = CHUNK / 256;

__device__ __forceinline__ void ins40s(float kj, u32 ki,
                                       float& lst_s, u32& lst_i,
                                       float& tau_s, int lane) {
  const int pos = (int)__popcll(__ballot(lst_s >= kj));
  const float shd = __uint_as_float(dpp_shr1(__float_as_uint(lst_s)));
  const u32  shi = dpp_shr1(lst_i);
  float nd = (lane == pos) ? kj : shd;
  u32   ni = (lane == pos) ? ki : shi;
  nd = (lane < pos) ? lst_s : nd;
  ni = (lane < pos) ? lst_i : ni;
  if (lane < LSLOTS) { lst_s = nd; lst_i = ni; }
  tau_s = rdlane_f(lst_s, LSLOTS - 1);
}

#define SUBW_INS(SX, JOFF)                                                   \
  {                                                                          \
    ull mm = __ballot((SX) > tau_s);                                         \
    while (mm) {                                                             \
      const int src = (int)__builtin_ctzll(mm);                              \
      const float k = rdlane_f((SX), src);                                   \
      if (k > tau_s)                                                         \
        ins40s(k, nb + ((u32)src << 2) + (JOFF), lst_s, lst_i, tau_s, lane); \
      mm &= mm - 1;                                                          \
      mm &= __ballot((SX) > tau_s);                                          \
    }                                                                        \
  }

__global__ __launch_bounds__(THREADS, 6) void knn_full(
    const float* __restrict__ P, const float* __restrict__ Q,
    const float* __restrict__ FT, float* __restrict__ out) {
#pragma clang fp contract(off)
  __shared__ float lds[4][CHUNK];

  const int tid  = threadIdx.x;
  const int lane = tid & 63;
  const int wid  = tid >> 6;
  const int bid  = blockIdx.x;
  const int xcd  = bid & 7;
  const int b    = xcd >> 1;
  const int tile = (bid >> 3) * 2 + (xcd & 1);
  const int m    = tile * WPB + wid;

  const float* Pb = P + (size_t)b * 3 * Nn;
  const float* Qb = Q + (size_t)b * 3 * Mn;

  const float qx = Qb[m];
  const float qy = Qb[Mn + m];
  const float qz = Qb[2 * Mn + m];
  const float yyq = (qx * qx + qy * qy) + qz * qz;

  const int t4 = tid * 4;
  float lst_s = NEG_INF;
  u32   lst_i = 0u;
  float tau_s = NEG_INF;

  {
    float4 vx = *(const float4*)(Pb + t4);
    float4 vy = *(const float4*)(Pb + Nn + t4);
    float4 vz = *(const float4*)(Pb + 2 * Nn + t4);
    float4 vh;
    vh.x = -0.5f * ((vx.x * vx.x + vy.x * vy.x) + vz.x * vz.x);
    vh.y = -0.5f * ((vx.y * vx.y + vy.y * vy.y) + vz.y * vz.y);
    vh.z = -0.5f * ((vx.z * vx.z + vy.z * vy.z) + vz.z * vz.z);
    vh.w = -0.5f * ((vx.w * vx.w + vy.w * vy.w) + vz.w * vz.w);
    *(float4*)&lds[0][t4] = vx;
    *(float4*)&lds[1][t4] = vy;
    *(float4*)&lds[2][t4] = vz;
    *(float4*)&lds[3][t4] = vh;
  }
  __syncthreads();

  {
    const float x = lds[0][lane];
    const float y = lds[1][lane];
    const float z = lds[2][lane];
    const float h = lds[3][lane];
    const float s = fmaf(z, qz, fmaf(y, qy, fmaf(x, qx, h)));
    const u32 os = fenc(s);
    ull key = (((ull)(~os)) << 32) | (u32)lane;
    key = sort64_asc(key, lane);
    const int i0 = (int)(key & 0xffffffffull);
    const float sv = __shfl(s, i0);
    if (lane < LSLOTS) { lst_s = sv; lst_i = (u32)i0; }
    tau_s = rdlane_f(lst_s, LSLOTS - 1);
  }

  for (int ch = 0; ch < NCHUNK; ++ch) {
    const int n0 = ch * CHUNK;
    float4 nx, ny, nz;
    if (ch + 1 < NCHUNK) {
      nx = *(const float4*)(Pb + (n0 + CHUNK) + t4);
      ny = *(const float4*)(Pb + Nn + (n0 + CHUNK) + t4);
      nz = *(const float4*)(Pb + 2 * Nn + (n0 + CHUNK) + t4);
    }
#pragma unroll
    for (int g = 0; g < NGROUP; ++g) {
      const int p = g * 256 + lane * 4;
      const float4 rx = *(const float4*)&lds[0][p];
      const float4 ry = *(const float4*)&lds[1][p];
      const float4 rz = *(const float4*)&lds[2][p];
      const float4 rh = *(const float4*)&lds[3][p];
      float s0 = fmaf(rz.x, qz, fmaf(ry.x, qy, fmaf(rx.x, qx, rh.x)));
      float s1 = fmaf(rz.y, qz, fmaf(ry.y, qy, fmaf(rx.y, qx, rh.y)));
      float s2 = fmaf(rz.z, qz, fmaf(ry.z, qy, fmaf(rx.z, qx, rh.z)));
      float s3 = fmaf(rz.w, qz, fmaf(ry.w, qy, fmaf(rx.w, qx, rh.w)));
      if (ch == 0 && g == 0 && lane < 16) {
        s0 = s1 = s2 = s3 = NEG_INF;
      }
      const float smax = fmaxf(fmaxf(s0, s1), fmaxf(s2, s3));
      if (__any(smax > tau_s)) {
        const u32 nb = (u32)(n0 + g * 256);
        SUBW_INS(s0, 0u)
        SUBW_INS(s1, 1u)
        SUBW_INS(s2, 2u)
        SUBW_INS(s3, 3u)
      }
    }
    __syncthreads();
    if (ch + 1 < NCHUNK) {
      float4 vh;
      vh.x = -0.5f * ((nx.x * nx.x + ny.x * ny.x) + nz.x * nz.x);
      vh.y = -0.5f * ((nx.y * nx.y + ny.y * ny.y) + nz.y * nz.y);
      vh.z = -0.5f * ((nx.z * nx.z + ny.z * ny.z) + nz.z * nz.z);
      vh.w = -0.5f * ((nx.w * nx.w + ny.w * ny.w) + nz.w * nz.w);
      *(float4*)&lds[0][t4] = nx;
      *(float4*)&lds[1][t4] = ny;
      *(float4*)&lds[2][t4] = nz;
      *(float4*)&lds[3][t4] = vh;
      __syncthreads();
    }
  }

  ull key;
  {
    const int idx = (int)lst_i;
    const float x = Pb[idx];
    const float y = Pb[Nn + idx];
    const float z = Pb[2 * Nn + idx];
    const float xx = (x * x + y * y) + z * z;
    const float dot = fmaf(z, qz, fmaf(y, qy, x * qx));
    const float d = fmaxf((xx + yyq) - 2.0f * dot, 0.0f);
    key = (lane < LSLOTS && lst_s > NEG_INF)
            ? ((((ull)__float_as_uint(d)) << 32) | (u32)idx)
            : ~0ull;
    key = sort64_asc(key, lane);
  }

  const size_t MK = (size_t)Mn * Kn;
  float* outb = out + (size_t)b * (3 + Cn) * MK;
  if (lane < 32) {
    const int idx = (int)(key & 0xFFFFFFFFull);
    const float px = Pb[idx];
    const float py = Pb[Nn + idx];
    const float pz = Pb[2 * Nn + idx];
    outb[0 * MK + (size_t)m * Kn + lane] = px - qx;
    outb[1 * MK + (size_t)m * Kn + lane] = py - qy;
    outb[2 * MK + (size_t)m * Kn + lane] = pz - qz;
  }
  const float* FTb = FT + (size_t)b * Nn * Cn;
  const int r  = lane & 15;
  const int qh = lane >> 4;
#pragma unroll
  for (int p2 = 0; p2 < 2; ++p2) {
    const int k = p2 * 16 + r;
    const int idxk = (int)(__shfl(key, k) & 0xFFFFFFFFull);
    const float* row = FTb + (size_t)idxk * Cn;
    float4 v[4];
#pragma unroll
    for (int i = 0; i < 4; ++i)
      v[i] = *(const float4*)(row + (qh + 4 * i) * 4);
#pragma unroll
    for (int i = 0; i < 4; ++i) {
      const int c = (qh + 4 * i) * 4;
      float* o = outb + (size_t)(3 + c) * MK + (size_t)m * Kn + k;
      o[0 * MK] = v[i].x;
      o[1 * MK] = v[i].y;
      o[2 * MK] = v[i].z;
      o[3 * MK] = v[i].w;
    }
  }
}

extern "C" void kernel_launch(void* const* d_in, const int* in_sizes, int n_in,
                              void* d_out, int out_size, void* d_ws, size_t ws_size,
                              hipStream_t stream) {
  (void)in_sizes; (void)n_in; (void)out_size;
  const float* P = (const float*)d_in[0];
  const float* Q = (const float*)d_in[1];
  const float* F = (const float*)d_in[2];
  float* out = (float*)d_out;
  char* ws = (char*)d_ws;

  const size_t FT_OFF  = 0;
  const size_t PTS_OFF = 16777216;                   // FT: 4*64*16384*4
  const size_t IDX_OFF = PTS_OFF + 1048576;          // pts4: 4*16384*16
  const size_t BS_OFF  = IDX_OFF + 262144;           // pidx: 4*16384*4
  const size_t CUR_OFF = BS_OFF + (size_t)Bn * 4097 * 4;
  const size_t BB_OFF  = CUR_OFF + (size_t)Bn * 4097 * 4;
  const size_t NEED    = BB_OFF + (size_t)Bn * 8 * 4;

  float* FT = (float*)(ws + FT_OFF);
  hipLaunchKernelGGL(transpose_f, dim3(256), dim3(256), 0, stream, F, FT);

  if (ws_size >= NEED) {
    float4* pts4 = (float4*)(ws + PTS_OFF);
    u32* pidx = (u32*)(ws + IDX_OFF);
    u32* bs   = (u32*)(ws + BS_OFF);
    u32* cur  = (u32*)(ws + CUR_OFF);
    u32* bb   = (u32*)(ws + BB_OFF);
    hipLaunchKernelGGL(k_init,    dim3(1),   dim3(1024), 0, stream, cur, bb);
    hipLaunchKernelGGL(k_bbox,    dim3(256), dim3(256),  0, stream, P, bb);
    hipLaunchKernelGGL(k_hist,    dim3(256), dim3(256),  0, stream, P, bb, cur);
    hipLaunchKernelGGL(k_scan,    dim3(Bn),  dim3(1024), 0, stream, cur, bs);
    hipLaunchKernelGGL(k_scatter, dim3(256), dim3(256),  0, stream, P, bb, cur,
                       pts4, pidx);
    hipLaunchKernelGGL(knn_bin, dim3(Bn * Mn / WPB), dim3(THREADS), 0, stream,
                       P, Q, FT, pts4, pidx, bs, bb, out);
  } else {
    hipLaunchKernelGGL(knn_full, dim3(Bn * Mn / WPB), dim3(THREADS), 0, stream,
                       P, Q, FT, out);
  }
}